// Round 10
// baseline (102.120 us; speedup 1.0000x reference)
//
#include <hip/hip_runtime.h>
#include <math.h>

// Problem constants (match reference)
#define B_SZ   4096
#define NMAX_SZ 64
#define H_SZ   768      // = 3 chunks of 256 floats; lane owns 4 floats per chunk
#define Q_SZ   16384
#define S_SZ   256

typedef float f4 __attribute__((ext_vector_type(4)));

// nontemporal float4 load (streaming read-once data: skip cache pollution).
// NOTE: because NT bypasses cache, every issued load is real DRAM traffic --
// all prefetches MUST be guarded, never clamped-and-re-read (R9 lesson:
// clamped tail prefetches cost ~30% extra DRAM bytes).
__device__ __forceinline__ f4 ldnt(const float* p) {
  return __builtin_nontemporal_load((const f4*)p);
}
__device__ __forceinline__ float dot4(const f4 a, const f4 b) {
  const f4 p = a * b;
  return p[0] + p[1] + p[2] + p[3];
}

// ---------------------------------------------------------------------------
// Kernel 1: fused attention-pool, 3-dot scalar form. One block per b.
// Algebra: emb.w = sum_n e_n (x_n.w) / sum e_n -> per row only THREE scalars
// (s=x.qw', u=x.wm1, v=x.wm2); row registers die after their dot FMAs.
// NO-MAX softmax (scores bounded |s|<~3; reference's max-shift & qb cancel).
// Wave w owns contiguous rows [len*w/4, len*(w+1)/4). Lane l owns floats
// {4l..4l+3} of each 256-float chunk -> 1 KB contiguous wave bursts.
// GUARDED prefetch (wave-uniform branches): no load is ever issued for a row
// that isn't live -> DRAM read == live bytes exactly (~409 MB).
// Outputs d1[b]=emb.wm_w[:H], d2[b]=emb.wm_w[H:].
// ---------------------------------------------------------------------------
__global__ __launch_bounds__(256, 4) void merge_dots_kernel(
    const float* __restrict__ padded, const float* __restrict__ qw,
    const float* __restrict__ wmw, const int* __restrict__ lengths,
    float* __restrict__ d1, float* __restrict__ d2) {
  const int b = blockIdx.x;
  const int t = threadIdx.x;
  const int lane = t & 63;
  const int w = t >> 6;
  const int len = lengths[b];
  const int o0 = 4 * lane;        // chunk 0 offset
  const int o1 = 256 + 4 * lane;  // chunk 1 offset
  const int o2 = 512 + 4 * lane;  // chunk 2 offset
  const float LOG2E = 1.4426950408889634f;

  __shared__ float sU[4], sV[4], sL[4];

  // weight fragments: qw (log2e-scaled), wm_w halves
  const f4 g0 = *(const f4*)(qw + o0) * LOG2E;
  const f4 g1 = *(const f4*)(qw + o1) * LOG2E;
  const f4 g2 = *(const f4*)(qw + o2) * LOG2E;
  const f4 u0 = *(const f4*)(wmw + o0);
  const f4 u1 = *(const f4*)(wmw + o1);
  const f4 u2 = *(const f4*)(wmw + o2);
  const f4 v0 = *(const f4*)(wmw + H_SZ + o0);
  const f4 v1 = *(const f4*)(wmw + H_SZ + o1);
  const f4 v2 = *(const f4*)(wmw + H_SZ + o2);

  // wave w's contiguous row range [lo, hi) -- exact partition of [0, len)
  const int lo = (len * w) >> 2;
  const int hi = (len * (w + 1)) >> 2;
  const int cnt = hi - lo;
  const float* wbase = padded + (size_t)b * (NMAX_SZ * H_SZ) + (size_t)lo * H_SZ;

  float U = 0.f, V = 0.f, l = 0.f;

  if (cnt > 0) {
    const f4 z = {0.f, 0.f, 0.f, 0.f};
    // current pair: row 0 always live; row 1 guarded (no clamp re-read)
    f4 xA0 = ldnt(wbase + o0), xA1 = ldnt(wbase + o1), xA2 = ldnt(wbase + o2);
    f4 xB0 = z, xB1 = z, xB2 = z;
    if (cnt > 1) {
      const float* rB = wbase + H_SZ;
      xB0 = ldnt(rB + o0); xB1 = ldnt(rB + o1); xB2 = ldnt(rB + o2);
    }

    for (int k = 0; k < cnt; k += 2) {
      // guarded prefetch of rows k+2, k+3 (wave-uniform branches; zeros are
      // numerically safe: tail eB guard annihilates their contribution)
      f4 nA0 = z, nA1 = z, nA2 = z, nB0 = z, nB1 = z, nB2 = z;
      if (k + 2 < cnt) {
        const float* fA = wbase + (size_t)(k + 2) * H_SZ;
        nA0 = ldnt(fA + o0); nA1 = ldnt(fA + o1); nA2 = ldnt(fA + o2);
      }
      if (k + 3 < cnt) {
        const float* fB = wbase + (size_t)(k + 3) * H_SZ;
        nB0 = ldnt(fB + o0); nB1 = ldnt(fB + o1); nB2 = ldnt(fB + o2);
      }

      // six dots; row registers die here
      float sa_ = dot4(xA0, g0) + dot4(xA1, g1) + dot4(xA2, g2);
      float ua_ = dot4(xA0, u0) + dot4(xA1, u1) + dot4(xA2, u2);
      float va_ = dot4(xA0, v0) + dot4(xA1, v1) + dot4(xA2, v2);
      float sb_ = dot4(xB0, g0) + dot4(xB1, g1) + dot4(xB2, g2);
      float ub_ = dot4(xB0, u0) + dot4(xB1, u1) + dot4(xB2, u2);
      float vb_ = dot4(xB0, v0) + dot4(xB1, v1) + dot4(xB2, v2);

      // six independent butterfly reduce chains, interleaved (deep ILP)
#pragma unroll
      for (int off = 32; off > 0; off >>= 1) {
        sa_ += __shfl_xor(sa_, off);
        sb_ += __shfl_xor(sb_, off);
        ua_ += __shfl_xor(ua_, off);
        ub_ += __shfl_xor(ub_, off);
        va_ += __shfl_xor(va_, off);
        vb_ += __shfl_xor(vb_, off);
      }

      const float eA = exp2f(sa_);
      const float eB = (k + 1 < cnt) ? exp2f(sb_) : 0.f;  // invalid row -> 0
      l += eA + eB;
      U = fmaf(eA, ua_, fmaf(eB, ub_, U));
      V = fmaf(eA, va_, fmaf(eB, vb_, V));

      xA0 = nA0; xA1 = nA1; xA2 = nA2;
      xB0 = nB0; xB1 = nB1; xB2 = nB2;
    }
  }

  // cross-wave merge: 3 scalars per wave (post-butterfly values are
  // wave-uniform; lane 0 publishes)
  if (lane == 0) { sU[w] = U; sV[w] = V; sL[w] = l; }
  __syncthreads();
  if (t == 0) {
    const float Ut = sU[0] + sU[1] + sU[2] + sU[3];
    const float Vt = sV[0] + sV[1] + sV[2] + sV[3];
    const float Lt = sL[0] + sL[1] + sL[2] + sL[3];  // > 0 since len >= 1
    const float inv = 1.f / Lt;
    d1[b] = Ut * inv;
    d2[b] = Vt * inv;
  }
}

// ---------------------------------------------------------------------------
// Kernel 2 (fused logits+segment): one block per segment s. The per-segment
// source term d1[cni[s]] is block-uniform; per-query logit is computed
// inline from the L2-resident d2/npi/labels. Two passes: max, then sums.
// ---------------------------------------------------------------------------
__global__ __launch_bounds__(256) void segment_kernel(
    const float* __restrict__ d1, const float* __restrict__ d2,
    const float* __restrict__ wmb,
    const int* __restrict__ npi, const int* __restrict__ cni,
    const int* __restrict__ npt, const int* __restrict__ labels,
    float* __restrict__ seg_term, float* __restrict__ seg_has) {
  const int s = blockIdx.x;
  const int t = threadIdx.x;
  const int lane = t & 63, wid = t >> 6;
  __shared__ float rg[4], rp[4], sa4[4], sp4[4], cp4[4];

  const float base = d1[cni[s]] + wmb[0];  // block-uniform source dot + bias

  float gmax = -INFINITY, pmax = -INFINITY;
  for (int q = t; q < Q_SZ; q += 256) {
    if (npt[q] == s) {
      const float lg = (base + d2[npi[q]]) * 10.f;  // /TEMP
      gmax = fmaxf(gmax, lg);
      if (labels[q] == 1) pmax = fmaxf(pmax, lg);
    }
  }
#pragma unroll
  for (int off = 32; off > 0; off >>= 1) {
    gmax = fmaxf(gmax, __shfl_xor(gmax, off));
    pmax = fmaxf(pmax, __shfl_xor(pmax, off));
  }
  if (lane == 0) { rg[wid] = gmax; rp[wid] = pmax; }
  __syncthreads();
  gmax = fmaxf(fmaxf(rg[0], rg[1]), fmaxf(rg[2], rg[3]));
  pmax = fmaxf(fmaxf(rp[0], rp[1]), fmaxf(rp[2], rp[3]));
  const float gmaxs = (gmax == -INFINITY) ? 0.f : gmax;
  const float pmaxs = (pmax == -INFINITY) ? 0.f : pmax;

  float sa = 0.f, sp = 0.f, cnt = 0.f;
  for (int q = t; q < Q_SZ; q += 256) {
    if (npt[q] == s) {
      const float lg = (base + d2[npi[q]]) * 10.f;
      sa += expf(lg - gmaxs);
      if (labels[q] == 1) { sp += expf(lg - pmaxs); cnt += 1.f; }
    }
  }
#pragma unroll
  for (int off = 32; off > 0; off >>= 1) {
    sa += __shfl_xor(sa, off);
    sp += __shfl_xor(sp, off);
    cnt += __shfl_xor(cnt, off);
  }
  if (lane == 0) { sa4[wid] = sa; sp4[wid] = sp; cp4[wid] = cnt; }
  __syncthreads();
  if (t == 0) {
    sa = sa4[0] + sa4[1] + sa4[2] + sa4[3];
    sp = sp4[0] + sp4[1] + sp4[2] + sp4[3];
    cnt = cp4[0] + cp4[1] + cp4[2] + cp4[3];
    const bool haspos = cnt > 0.f;
    float term = 0.f;
    if (haspos) term = (logf(sa) + gmaxs) - (logf(sp) + pmaxs);
    seg_term[s] = term;
    seg_has[s] = haspos ? 1.f : 0.f;
  }
}

// ---------------------------------------------------------------------------
// Kernel 3: loss = sum(term) / max(sum(has), 1)
// ---------------------------------------------------------------------------
__global__ __launch_bounds__(256) void finalize_kernel(
    const float* __restrict__ seg_term, const float* __restrict__ seg_has,
    float* __restrict__ out) {
  const int t = threadIdx.x;
  const int lane = t & 63, wid = t >> 6;
  __shared__ float rt[4], rh[4];
  float v = seg_term[t];
  float h = seg_has[t];
#pragma unroll
  for (int off = 32; off > 0; off >>= 1) {
    v += __shfl_xor(v, off);
    h += __shfl_xor(h, off);
  }
  if (lane == 0) { rt[wid] = v; rh[wid] = h; }
  __syncthreads();
  if (t == 0) {
    const float total = rt[0] + rt[1] + rt[2] + rt[3];
    const float nv = rh[0] + rh[1] + rh[2] + rh[3];
    out[0] = total / fmaxf(nv, 1.f);
  }
}

extern "C" void kernel_launch(void* const* d_in, const int* in_sizes, int n_in,
                              void* d_out, int out_size, void* d_ws, size_t ws_size,
                              hipStream_t stream) {
  const float* padded  = (const float*)d_in[0];
  const float* qw      = (const float*)d_in[1];
  // d_in[2] = qb: cancels identically in softmax -> unused
  const float* wmw     = (const float*)d_in[3];
  const float* wmb     = (const float*)d_in[4];
  const int*   lengths = (const int*)d_in[5];
  const int*   npi     = (const int*)d_in[6];
  const int*   cni     = (const int*)d_in[7];
  const int*   npt     = (const int*)d_in[8];
  const int*   labels  = (const int*)d_in[9];
  float* out = (float*)d_out;

  // workspace layout (all fully written before read each call)
  float* d1       = (float*)d_ws;          // B
  float* d2       = d1 + B_SZ;             // B
  float* seg_term = d2 + B_SZ;             // S
  float* seg_has  = seg_term + S_SZ;       // S

  merge_dots_kernel<<<B_SZ, 256, 0, stream>>>(padded, qw, wmw, lengths, d1, d2);
  segment_kernel<<<S_SZ, 256, 0, stream>>>(d1, d2, wmb, npi, cni, npt, labels,
                                           seg_term, seg_has);
  finalize_kernel<<<1, 256, 0, stream>>>(seg_term, seg_has, out);
}

// Round 11
// 90.622 us; speedup vs baseline: 1.1269x; 1.1269x over previous
//
#include <hip/hip_runtime.h>
#include <math.h>

// Problem constants (match reference)
#define B_SZ   4096
#define NMAX_SZ 64
#define H_SZ   768      // = 3 chunks of 256 floats; lane owns 4 floats per chunk
#define Q_SZ   16384
#define S_SZ   256

typedef float f4 __attribute__((ext_vector_type(4)));

// nontemporal float4 load (streaming read-once data)
__device__ __forceinline__ f4 ldnt(const float* p) {
  return __builtin_nontemporal_load((const f4*)p);
}
__device__ __forceinline__ float dot4(const f4 a, const f4 b) {
  const f4 p = a * b;
  return p[0] + p[1] + p[2] + p[3];
}

// ---------------------------------------------------------------------------
// Kernel 1: fused attention-pool, 3-dot scalar form (best measured config,
// R9: clamped prefetch -- duplicate tail loads are merged by the memory
// system and cost nothing; R10's guards only added branch overhead).
// One block per b. Algebra: emb.w = sum_n e_n (x_n.w) / sum e_n -> per row
// only THREE scalars (s=x.qw', u=x.wm1, v=x.wm2). NO-MAX softmax (scores
// bounded |s|<~3; reference's max-shift & qb cancel identically). Wave w
// owns contiguous rows [len*w/4, len*(w+1)/4). Lane l owns floats {4l..4l+3}
// of each 256-float chunk -> 1 KB contiguous wave bursts, NT loads.
// Outputs d1[b]=emb.wm_w[:H], d2[b]=emb.wm_w[H:].
// Measured: ~90 us at ~4.5 TB/s pure-read -- the empirical ceiling for this
// pattern (7 structural variants converge there; copy bench's 6.3 TB/s is
// read+write pipelined, not pure-read).
// ---------------------------------------------------------------------------
__global__ __launch_bounds__(256, 4) void merge_dots_kernel(
    const float* __restrict__ padded, const float* __restrict__ qw,
    const float* __restrict__ wmw, const int* __restrict__ lengths,
    float* __restrict__ d1, float* __restrict__ d2) {
  const int b = blockIdx.x;
  const int t = threadIdx.x;
  const int lane = t & 63;
  const int w = t >> 6;
  const int len = lengths[b];
  const int o0 = 4 * lane;        // chunk 0 offset
  const int o1 = 256 + 4 * lane;  // chunk 1 offset
  const int o2 = 512 + 4 * lane;  // chunk 2 offset
  const float LOG2E = 1.4426950408889634f;

  __shared__ float sU[4], sV[4], sL[4];

  // weight fragments: qw (log2e-scaled), wm_w halves
  const f4 g0 = *(const f4*)(qw + o0) * LOG2E;
  const f4 g1 = *(const f4*)(qw + o1) * LOG2E;
  const f4 g2 = *(const f4*)(qw + o2) * LOG2E;
  const f4 u0 = *(const f4*)(wmw + o0);
  const f4 u1 = *(const f4*)(wmw + o1);
  const f4 u2 = *(const f4*)(wmw + o2);
  const f4 v0 = *(const f4*)(wmw + H_SZ + o0);
  const f4 v1 = *(const f4*)(wmw + H_SZ + o1);
  const f4 v2 = *(const f4*)(wmw + H_SZ + o2);

  // wave w's contiguous row range [lo, hi) -- exact partition of [0, len)
  const int lo = (len * w) >> 2;
  const int hi = (len * (w + 1)) >> 2;
  const int cnt = hi - lo;
  const float* wbase = padded + (size_t)b * (NMAX_SZ * H_SZ) + (size_t)lo * H_SZ;

  float U = 0.f, V = 0.f, l = 0.f;

  if (cnt > 0) {
    // current pair (k=0 valid; k=1 clamped if cnt==1)
    const float* rA = wbase;
    const float* rB = wbase + (size_t)((1 < cnt) ? 1 : 0) * H_SZ;
    f4 xA0 = ldnt(rA + o0), xA1 = ldnt(rA + o1), xA2 = ldnt(rA + o2);
    f4 xB0 = ldnt(rB + o0), xB1 = ldnt(rB + o1), xB2 = ldnt(rB + o2);

    for (int k = 0; k < cnt; k += 2) {
      // prefetch next pair (clamped; duplicates merge in the MC)
      const int pA = (k + 2 < cnt) ? k + 2 : cnt - 1;
      const int pB = (k + 3 < cnt) ? k + 3 : cnt - 1;
      const float* fA = wbase + (size_t)pA * H_SZ;
      const float* fB = wbase + (size_t)pB * H_SZ;
      const f4 nA0 = ldnt(fA + o0), nA1 = ldnt(fA + o1), nA2 = ldnt(fA + o2);
      const f4 nB0 = ldnt(fB + o0), nB1 = ldnt(fB + o1), nB2 = ldnt(fB + o2);

      // six dots; row registers die here
      float sa_ = dot4(xA0, g0) + dot4(xA1, g1) + dot4(xA2, g2);
      float ua_ = dot4(xA0, u0) + dot4(xA1, u1) + dot4(xA2, u2);
      float va_ = dot4(xA0, v0) + dot4(xA1, v1) + dot4(xA2, v2);
      float sb_ = dot4(xB0, g0) + dot4(xB1, g1) + dot4(xB2, g2);
      float ub_ = dot4(xB0, u0) + dot4(xB1, u1) + dot4(xB2, u2);
      float vb_ = dot4(xB0, v0) + dot4(xB1, v1) + dot4(xB2, v2);

      // six independent butterfly reduce chains, interleaved (deep ILP)
#pragma unroll
      for (int off = 32; off > 0; off >>= 1) {
        sa_ += __shfl_xor(sa_, off);
        sb_ += __shfl_xor(sb_, off);
        ua_ += __shfl_xor(ua_, off);
        ub_ += __shfl_xor(ub_, off);
        va_ += __shfl_xor(va_, off);
        vb_ += __shfl_xor(vb_, off);
      }

      const float eA = exp2f(sa_);
      const float eB = (k + 1 < cnt) ? exp2f(sb_) : 0.f;  // invalid row -> 0
      l += eA + eB;
      U = fmaf(eA, ua_, fmaf(eB, ub_, U));
      V = fmaf(eA, va_, fmaf(eB, vb_, V));

      xA0 = nA0; xA1 = nA1; xA2 = nA2;
      xB0 = nB0; xB1 = nB1; xB2 = nB2;
    }
  }

  // cross-wave merge: 3 scalars per wave (post-butterfly wave-uniform)
  if (lane == 0) { sU[w] = U; sV[w] = V; sL[w] = l; }
  __syncthreads();
  if (t == 0) {
    const float Ut = sU[0] + sU[1] + sU[2] + sU[3];
    const float Vt = sV[0] + sV[1] + sV[2] + sV[3];
    const float Lt = sL[0] + sL[1] + sL[2] + sL[3];  // > 0 since len >= 1
    const float inv = 1.f / Lt;
    d1[b] = Ut * inv;
    d2[b] = Vt * inv;
  }
}

// ---------------------------------------------------------------------------
// Kernel 2 (fused logits+segment, SINGLE-PASS online LSE): one block per
// segment s. d1[cni[s]] is block-uniform; per-query logit computed inline
// from L2-resident d2/npi/labels. One Q-scan carrying online (max,sum) for
// all-logits and pos-logits; butterfly + LDS merge. Finite sentinel -1e30
// (not -inf) so m_a - m_new is always finite (no NaN in the merge).
// ---------------------------------------------------------------------------
__global__ __launch_bounds__(256) void segment_kernel(
    const float* __restrict__ d1, const float* __restrict__ d2,
    const float* __restrict__ wmb,
    const int* __restrict__ npi, const int* __restrict__ cni,
    const int* __restrict__ npt, const int* __restrict__ labels,
    float* __restrict__ seg_term, float* __restrict__ seg_has) {
  const int s = blockIdx.x;
  const int t = threadIdx.x;
  const int lane = t & 63, wid = t >> 6;
  __shared__ float sgm[4], sgs[4], spm[4], sps[4], scn[4];

  const float base = d1[cni[s]] + wmb[0];  // block-uniform source dot + bias

  float gm = -1e30f, gs = 0.f;   // online LSE state, all logits
  float pm = -1e30f, ps = 0.f;   // online LSE state, pos logits
  float cn = 0.f;

  for (int q = t; q < Q_SZ; q += 256) {
    if (npt[q] == s) {
      const float lg = (base + d2[npi[q]]) * 10.f;  // /TEMP
      if (lg > gm) { gs = gs * __expf(gm - lg) + 1.f; gm = lg; }
      else         { gs += __expf(lg - gm); }
      if (labels[q] == 1) {
        if (lg > pm) { ps = ps * __expf(pm - lg) + 1.f; pm = lg; }
        else         { ps += __expf(lg - pm); }
        cn += 1.f;
      }
    }
  }

  // butterfly merge of (m, s) pairs across 64 lanes
#pragma unroll
  for (int off = 32; off > 0; off >>= 1) {
    const float gmo = __shfl_xor(gm, off), gso = __shfl_xor(gs, off);
    const float pmo = __shfl_xor(pm, off), pso = __shfl_xor(ps, off);
    cn += __shfl_xor(cn, off);
    float m = fmaxf(gm, gmo);
    gs = gs * __expf(gm - m) + gso * __expf(gmo - m);
    gm = m;
    m = fmaxf(pm, pmo);
    ps = ps * __expf(pm - m) + pso * __expf(pmo - m);
    pm = m;
  }
  if (lane == 0) { sgm[wid] = gm; sgs[wid] = gs; spm[wid] = pm; sps[wid] = ps; scn[wid] = cn; }
  __syncthreads();
  if (t == 0) {
    gm = sgm[0]; gs = sgs[0]; pm = spm[0]; ps = sps[0];
    float cnt = scn[0] + scn[1] + scn[2] + scn[3];
#pragma unroll
    for (int i = 1; i < 4; ++i) {
      float m = fmaxf(gm, sgm[i]);
      gs = gs * __expf(gm - m) + sgs[i] * __expf(sgm[i] - m);
      gm = m;
      m = fmaxf(pm, spm[i]);
      ps = ps * __expf(pm - m) + sps[i] * __expf(spm[i] - m);
      pm = m;
    }
    const bool haspos = cnt > 0.f;
    seg_term[s] = haspos ? ((logf(gs) + gm) - (logf(ps) + pm)) : 0.f;
    seg_has[s] = haspos ? 1.f : 0.f;
  }
}

// ---------------------------------------------------------------------------
// Kernel 3: loss = sum(term) / max(sum(has), 1)
// ---------------------------------------------------------------------------
__global__ __launch_bounds__(256) void finalize_kernel(
    const float* __restrict__ seg_term, const float* __restrict__ seg_has,
    float* __restrict__ out) {
  const int t = threadIdx.x;
  const int lane = t & 63, wid = t >> 6;
  __shared__ float rt[4], rh[4];
  float v = seg_term[t];
  float h = seg_has[t];
#pragma unroll
  for (int off = 32; off > 0; off >>= 1) {
    v += __shfl_xor(v, off);
    h += __shfl_xor(h, off);
  }
  if (lane == 0) { rt[wid] = v; rh[wid] = h; }
  __syncthreads();
  if (t == 0) {
    const float total = rt[0] + rt[1] + rt[2] + rt[3];
    const float nv = rh[0] + rh[1] + rh[2] + rh[3];
    out[0] = total / fmaxf(nv, 1.f);
  }
}

extern "C" void kernel_launch(void* const* d_in, const int* in_sizes, int n_in,
                              void* d_out, int out_size, void* d_ws, size_t ws_size,
                              hipStream_t stream) {
  const float* padded  = (const float*)d_in[0];
  const float* qw      = (const float*)d_in[1];
  // d_in[2] = qb: cancels identically in softmax -> unused
  const float* wmw     = (const float*)d_in[3];
  const float* wmb     = (const float*)d_in[4];
  const int*   lengths = (const int*)d_in[5];
  const int*   npi     = (const int*)d_in[6];
  const int*   cni     = (const int*)d_in[7];
  const int*   npt     = (const int*)d_in[8];
  const int*   labels  = (const int*)d_in[9];
  float* out = (float*)d_out;

  // workspace layout (all fully written before read each call)
  float* d1       = (float*)d_ws;          // B
  float* d2       = d1 + B_SZ;             // B
  float* seg_term = d2 + B_SZ;             // S
  float* seg_has  = seg_term + S_SZ;       // S

  merge_dots_kernel<<<B_SZ, 256, 0, stream>>>(padded, qw, wmw, lengths, d1, d2);
  segment_kernel<<<S_SZ, 256, 0, stream>>>(d1, d2, wmb, npi, cni, npt, labels,
                                           seg_term, seg_has);
  finalize_kernel<<<1, 256, 0, stream>>>(seg_term, seg_has, out);
}